// Round 4
// baseline (864.581 us; speedup 1.0000x reference)
//
#include <hip/hip_runtime.h>
#include <hip/hip_bf16.h>

#define B_   128
#define C_   2048
#define S_   196
#define HID_ 1024
#define T_   20

typedef __attribute__((ext_vector_type(8))) short s16x8;   // 8 bf16 (4 VGPRs)
typedef __attribute__((ext_vector_type(4))) float f32x4_t; // MFMA 16x16 acc
typedef __attribute__((ext_vector_type(4))) unsigned short us4;

__device__ __forceinline__ float fast_tanh(float x) {
  float e = __expf(2.f * x);
  return 1.f - 2.f / (e + 1.f);
}
__device__ __forceinline__ unsigned short f2bf(float x) {
  __hip_bfloat16 h = __float2bfloat16(x);
  return *reinterpret_cast<unsigned short*>(&h);
}
__device__ __forceinline__ float bf2f(unsigned short s) {
  unsigned int b = ((unsigned int)s) << 16;
  return __builtin_bit_cast(float, b);
}
__device__ __forceinline__ void gl_lds16(const short* g, short* l) {
  __builtin_amdgcn_global_load_lds(
      (const __attribute__((address_space(1))) void*)g,
      (__attribute__((address_space(3))) void*)l, 16, 0, 0);
}

// ---------------- fp32 -> bf16 weight convert ----------------
__global__ void cvt_k(const float* __restrict__ in, __hip_bfloat16* __restrict__ out, int n) {
  int i = (blockIdx.x * 256 + threadIdx.x) * 4;
  if (i >= n) return;
  float4 v = *(const float4*)(in + i);
  out[i + 0] = __float2bfloat16(v.x);
  out[i + 1] = __float2bfloat16(v.y);
  out[i + 2] = __float2bfloat16(v.z);
  out[i + 3] = __float2bfloat16(v.w);
}

// ---------------- v_i [b,c,s] fp32 -> viT [b,s,c] bf16 ----------------
__global__ void transpose_k(const float* __restrict__ src, __hip_bfloat16* __restrict__ dst) {
  __shared__ float tile[32][65];
  int b  = blockIdx.z;
  int c0 = blockIdx.x * 64;
  int s0 = blockIdx.y * 32;
  int t  = threadIdx.x;
  int cl = t >> 3, sq = t & 7;
  const float* sp = src + ((size_t)b * C_ + c0) * S_ + s0;
  #pragma unroll
  for (int p = 0; p < 2; p++) {
    int c = cl + p * 32;
    int s = sq * 4;
    if (s0 + s < S_) {
      float4 v = *(const float4*)(sp + (size_t)c * S_ + s);
      tile[s + 0][c] = v.x; tile[s + 1][c] = v.y;
      tile[s + 2][c] = v.z; tile[s + 3][c] = v.w;
    }
  }
  __syncthreads();
  int sl = t >> 4, cq = t & 15;
  #pragma unroll
  for (int p = 0; p < 2; p++) {
    int s = sl + p * 16;
    if (s0 + s < S_) {
      us4 v;
      v.x = f2bf(tile[s][cq * 4 + 0]); v.y = f2bf(tile[s][cq * 4 + 1]);
      v.z = f2bf(tile[s][cq * 4 + 2]); v.w = f2bf(tile[s][cq * 4 + 3]);
      *(us4*)(dst + ((size_t)b * S_ + s0 + s) * C_ + c0 + cq * 4) = v;
    }
  }
}

// ---------------- u[b,h] = mean_t v_q[b,t,h] ----------------
__global__ void umean_k(const float* __restrict__ vq, float* __restrict__ u) {
  int b = blockIdx.y;
  int h = blockIdx.x * 256 + threadIdx.x;
  const float* p = vq + (size_t)b * T_ * HID_ + h;
  float s = 0.f;
  #pragma unroll
  for (int t = 0; t < T_; t++) s += p[t * HID_];
  u[(size_t)b * HID_ + h] = s * (1.f / T_);
}

// ---------------- vqt[b,k] = sum_h u[b,h]*w_u[k,h] + b_u[k] ----------------
__global__ void vqt_k(const float* __restrict__ u, const float* __restrict__ wu,
                      const float* __restrict__ bu, float* __restrict__ out) {
  __shared__ float us[32][64];
  __shared__ float ws[64][65];
  int k0 = blockIdx.x * 64, b0 = blockIdx.y * 32;
  int tid = threadIdx.x;
  int kl = tid & 63, bg = tid >> 6;
  float acc[8];
  #pragma unroll
  for (int j = 0; j < 8; j++) acc[j] = 0.f;
  for (int h0 = 0; h0 < HID_; h0 += 64) {
    __syncthreads();
    for (int idx = tid; idx < 32 * 16; idx += 256) {
      int bi = idx >> 4, jj = (idx & 15) * 4;
      *(float4*)&us[bi][jj] = *(const float4*)&u[(size_t)(b0 + bi) * HID_ + h0 + jj];
    }
    for (int idx = tid; idx < 64 * 16; idx += 256) {
      int ki = idx >> 4, jj = (idx & 15) * 4;
      float4 v = *(const float4*)&wu[(size_t)(k0 + ki) * HID_ + h0 + jj];
      ws[ki][jj] = v.x; ws[ki][jj + 1] = v.y; ws[ki][jj + 2] = v.z; ws[ki][jj + 3] = v.w;
    }
    __syncthreads();
    #pragma unroll 8
    for (int h = 0; h < 64; h++) {
      float wv = ws[kl][h];
      #pragma unroll
      for (int j = 0; j < 8; j++) acc[j] += wv * us[bg * 8 + j][h];
    }
  }
  #pragma unroll
  for (int j = 0; j < 8; j++)
    out[(size_t)(b0 + bg * 8 + j) * HID_ + k0 + kl] = acc[j] + bu[k0 + kl];
}

// ---------------- main GEMM: out[s,n] = sum_k A[b,s,k] * W[n,k] ----------------
// Block: 256 thr = 4 waves (2 mg x 2 ng). Tile M=224 (196 valid, rows clamped)
// x N=128, BK=32. Wave tile 112x64: 7 A-frag + 4 B-frag ds_read_b128 per 28 MFMA
// (2.5x the reuse of r3's 14:13) -> MFMA-bound (~543 vs 518 LDS cyc per blk-iter).
// acc[7][4] = 112 VGPR; launch_bounds(256,3) -> 3 blocks/CU (LDS 24.5 KB).
// Hop epilogue: tanh -> softmax over all 224 rows: cross-wave (mg) combine via
// 2 KB LDS buffer; vi re-read from global (L2-hot: the K-loop just streamed it).
template<int KDIM, bool IS_HOP>
__global__ __launch_bounds__(256, 3)
void gemm_k(const __hip_bfloat16* __restrict__ Asrc,
            const __hip_bfloat16* __restrict__ Bw,
            const float* __restrict__ aux,      // l1: bias[1024]; hop: vqt[B][1024]
            __hip_bfloat16* __restrict__ vi_out,
            const __hip_bfloat16* __restrict__ vi_in,
            float* __restrict__ u) {
  constexpr int MSW = 7;                        // m-subtiles per wave
  __shared__ short a_lds[896 * 8];              // 224 rows x 4 chunk-slots
  __shared__ short b_lds[512 * 8];              // 128 rows x 4 chunk-slots
  __shared__ float redb[2][128][2];             // hop cross-wave reduce

  const int id = blockIdx.x;
  const int b  = (id & 3) | ((id >> 5) << 2);
  const int n0 = ((id >> 2) & 7) * 128;
  const int tid  = threadIdx.x;
  const int wv   = tid >> 6;
  const int mg   = wv >> 1;                     // m-group (rows mg*112 ..)
  const int ng   = wv & 1;                      // n-group (cols ng*64 ..)
  const int lane = tid & 63;
  const int ln   = lane & 15;
  const int quad = lane >> 4;
  const int qsw  = quad ^ ((ln >> 1) & 3);      // chunk-slot swizzle

  const short* Ab = (const short*)(Asrc + (size_t)b * S_ * KDIM);
  const short* Bb = (const short*)Bw + (size_t)n0 * KDIM;

  f32x4_t acc[MSW][4] = {};

  for (int k0 = 0; k0 < KDIM; k0 += 32) {
    __syncthreads();
    // A: 896 chunks (224 rows x 4), slot i holds global chunk (i&3)^((i>>3)&3)
    #pragma unroll
    for (int p = 0; p < 3; p++) {
      int i = tid + p * 256;
      int m = i >> 2;
      int q = (i & 3) ^ ((i >> 3) & 3);
      int mc = (m < S_) ? m : (S_ - 1);
      gl_lds16(Ab + (size_t)mc * KDIM + k0 + q * 8, &a_lds[i * 8]);
    }
    if (tid < 128) {
      int i = tid + 768;
      int m = i >> 2;
      int q = (i & 3) ^ ((i >> 3) & 3);
      int mc = (m < S_) ? m : (S_ - 1);
      gl_lds16(Ab + (size_t)mc * KDIM + k0 + q * 8, &a_lds[i * 8]);
    }
    // B: 512 chunks (128 rows x 4)
    #pragma unroll
    for (int p = 0; p < 2; p++) {
      int i = tid + p * 256;
      int n = i >> 2;
      int q = (i & 3) ^ ((i >> 3) & 3);
      gl_lds16(Bb + (size_t)n * KDIM + k0 + q * 8, &b_lds[i * 8]);
    }
    __syncthreads();
    s16x8 bf[4];
    #pragma unroll
    for (int j = 0; j < 4; j++)
      bf[j] = *(s16x8*)&b_lds[((ng * 64 + j * 16 + ln) * 4 + qsw) * 8];
    #pragma unroll
    for (int ms = 0; ms < MSW; ms++) {
      s16x8 af = *(s16x8*)&a_lds[((mg * 112 + ms * 16 + ln) * 4 + qsw) * 8];
      #pragma unroll
      for (int j = 0; j < 4; j++)
        acc[ms][j] = __builtin_amdgcn_mfma_f32_16x16x32_bf16(af, bf[j], acc[ms][j], 0, 0, 0);
    }
  }

  // C/D layout: col = lane&15, row = quad*4 + reg
  const int colb = ng * 64 + ln;                // + j*16; global col = n0 + colb + j*16
  if (!IS_HOP) {
    float bias[4];
    #pragma unroll
    for (int j = 0; j < 4; j++) bias[j] = aux[n0 + colb + j * 16];
    #pragma unroll
    for (int ms = 0; ms < MSW; ms++) {
      #pragma unroll
      for (int r = 0; r < 4; r++) {
        int row = mg * 112 + ms * 16 + quad * 4 + r;
        if (row < S_) {
          #pragma unroll
          for (int j = 0; j < 4; j++)
            vi_out[((size_t)b * S_ + row) * HID_ + n0 + colb + j * 16] =
                __float2bfloat16(fast_tanh(acc[ms][j][r] + bias[j]));
        }
      }
    }
  } else {
    float vq[4], mx[4];
    #pragma unroll
    for (int j = 0; j < 4; j++) {
      vq[j] = aux[(size_t)b * HID_ + n0 + colb + j * 16];
      mx[j] = -1e30f;
    }
    #pragma unroll
    for (int ms = 0; ms < MSW; ms++) {
      #pragma unroll
      for (int r = 0; r < 4; r++) {
        int row = mg * 112 + ms * 16 + quad * 4 + r;
        #pragma unroll
        for (int j = 0; j < 4; j++) {
          float v = (row < S_) ? fast_tanh(acc[ms][j][r] + vq[j]) : -1e30f;
          acc[ms][j][r] = v;
          mx[j] = fmaxf(mx[j], v);
        }
      }
    }
    #pragma unroll
    for (int j = 0; j < 4; j++) {
      mx[j] = fmaxf(mx[j], __shfl_xor(mx[j], 16));
      mx[j] = fmaxf(mx[j], __shfl_xor(mx[j], 32));
    }
    if (quad == 0) {
      #pragma unroll
      for (int j = 0; j < 4; j++) redb[mg][colb + j * 16][0] = mx[j];
    }
    __syncthreads();
    float gmx[4];
    #pragma unroll
    for (int j = 0; j < 4; j++)
      gmx[j] = fmaxf(mx[j], redb[1 - mg][colb + j * 16][0]);
    __syncthreads();                             // reads done before overwrite
    float den[4] = {}, num[4] = {};
    const __hip_bfloat16* vb = vi_in + (size_t)b * S_ * HID_;
    #pragma unroll
    for (int ms = 0; ms < MSW; ms++) {
      #pragma unroll
      for (int r = 0; r < 4; r++) {
        int row = mg * 112 + ms * 16 + quad * 4 + r;
        if (row < S_) {
          #pragma unroll
          for (int j = 0; j < 4; j++) {
            float e = __expf(acc[ms][j][r] - gmx[j]);
            den[j] += e;
            num[j] += e * __bfloat162float(vb[(size_t)row * HID_ + n0 + colb + j * 16]);
          }
        }
      }
    }
    #pragma unroll
    for (int j = 0; j < 4; j++) {
      den[j] += __shfl_xor(den[j], 16); den[j] += __shfl_xor(den[j], 32);
      num[j] += __shfl_xor(num[j], 16); num[j] += __shfl_xor(num[j], 32);
    }
    if (quad == 0) {
      #pragma unroll
      for (int j = 0; j < 4; j++) {
        redb[mg][colb + j * 16][0] = den[j];
        redb[mg][colb + j * 16][1] = num[j];
      }
    }
    __syncthreads();
    if (mg == 0 && quad == 0) {
      #pragma unroll
      for (int j = 0; j < 4; j++) {
        int c = colb + j * 16;
        float d = redb[0][c][0] + redb[1][c][0];
        float n = redb[0][c][1] + redb[1][c][1];
        u[(size_t)b * HID_ + n0 + c] += n / d;
      }
    }
  }
}

extern "C" void kernel_launch(void* const* d_in, const int* in_sizes, int n_in,
                              void* d_out, int out_size, void* d_ws, size_t ws_size,
                              hipStream_t stream) {
  const float* v_i   = (const float*)d_in[0];
  const float* v_q   = (const float*)d_in[1];
  const float* l1_w  = (const float*)d_in[2];
  const float* l1_b  = (const float*)d_in[3];
  const float* w_vi0 = (const float*)d_in[4];
  const float* w_u0  = (const float*)d_in[5];
  const float* b_u0  = (const float*)d_in[6];
  const float* w_vi1 = (const float*)d_in[7];
  const float* w_u1  = (const float*)d_in[8];
  const float* b_u1  = (const float*)d_in[9];
  float* u = (float*)d_out;

  __hip_bfloat16* viT  = (__hip_bfloat16*)d_ws;                    // [B][S][C]
  __hip_bfloat16* vi   = viT + (size_t)B_ * S_ * C_;               // [B][S][HID]
  float*          vqt  = (float*)(vi + (size_t)B_ * S_ * HID_);    // [B][HID]
  __hip_bfloat16* l1wb = (__hip_bfloat16*)(vqt + (size_t)B_ * HID_);
  __hip_bfloat16* wv0b = l1wb + (size_t)HID_ * C_;
  __hip_bfloat16* wv1b = wv0b + (size_t)HID_ * HID_;

  cvt_k<<<dim3((HID_ * C_) / 1024), 256, 0, stream>>>(l1_w, l1wb, HID_ * C_);
  cvt_k<<<dim3((HID_ * HID_) / 1024), 256, 0, stream>>>(w_vi0, wv0b, HID_ * HID_);
  cvt_k<<<dim3((HID_ * HID_) / 1024), 256, 0, stream>>>(w_vi1, wv1b, HID_ * HID_);
  transpose_k<<<dim3(C_ / 64, 7, B_), 256, 0, stream>>>(v_i, viT);
  umean_k<<<dim3(HID_ / 256, B_), 256, 0, stream>>>(v_q, u);

  gemm_k<C_, false><<<dim3(1024), 256, 0, stream>>>(viT, l1wb, l1_b, vi, nullptr, nullptr);

  vqt_k<<<dim3(16, 4), 256, 0, stream>>>(u, w_u0, b_u0, vqt);
  gemm_k<HID_, true><<<dim3(1024), 256, 0, stream>>>(vi, wv0b, vqt, nullptr, vi, u);

  vqt_k<<<dim3(16, 4), 256, 0, stream>>>(u, w_u1, b_u1, vqt);
  gemm_k<HID_, true><<<dim3(1024), 256, 0, stream>>>(vi, wv1b, vqt, nullptr, vi, u);
}

// Round 5
// 859.313 us; speedup vs baseline: 1.0061x; 1.0061x over previous
//
#include <hip/hip_runtime.h>
#include <hip/hip_bf16.h>

#define B_   128
#define C_   2048
#define S_   196
#define HID_ 1024
#define T_   20

typedef __attribute__((ext_vector_type(8))) short s16x8;   // 8 bf16 (4 VGPRs)
typedef __attribute__((ext_vector_type(4))) float f32x4_t; // MFMA 16x16 acc
typedef __attribute__((ext_vector_type(4))) unsigned short us4;

__device__ __forceinline__ float fast_tanh(float x) {
  float e = __expf(2.f * x);
  return 1.f - 2.f / (e + 1.f);
}
__device__ __forceinline__ unsigned short f2bf(float x) {
  __hip_bfloat16 h = __float2bfloat16(x);
  return *reinterpret_cast<unsigned short*>(&h);
}
__device__ __forceinline__ void gl_lds16(const short* g, short* l) {
  __builtin_amdgcn_global_load_lds(
      (const __attribute__((address_space(1))) void*)g,
      (__attribute__((address_space(3))) void*)l, 16, 0, 0);
}

// ---------------- fp32 -> bf16 convert, 3 sources, contiguous dst ----------------
__global__ void cvt3_k(const float* __restrict__ s0, const float* __restrict__ s1,
                       const float* __restrict__ s2, __hip_bfloat16* __restrict__ dst) {
  // dst layout: [0, 2M) <- s0, [2M, 3M) <- s1, [3M, 4M) <- s2
  int i = (blockIdx.x * 256 + threadIdx.x) * 4;
  const int N0 = HID_ * C_, N1 = HID_ * HID_;
  const float* src;
  int off;
  if (i < N0)            { src = s0; off = i; }
  else if (i < N0 + N1)  { src = s1; off = i - N0; }
  else                   { src = s2; off = i - N0 - N1; }
  float4 v = *(const float4*)(src + off);
  dst[i + 0] = __float2bfloat16(v.x);
  dst[i + 1] = __float2bfloat16(v.y);
  dst[i + 2] = __float2bfloat16(v.z);
  dst[i + 3] = __float2bfloat16(v.w);
}

// ---------------- v_i [b,c,s] fp32 -> viT [b,s,c] bf16 ----------------
__global__ void transpose_k(const float* __restrict__ src, __hip_bfloat16* __restrict__ dst) {
  __shared__ float tile[32][65];
  int b  = blockIdx.z;
  int c0 = blockIdx.x * 64;
  int s0 = blockIdx.y * 32;
  int t  = threadIdx.x;
  int cl = t >> 3, sq = t & 7;
  const float* sp = src + ((size_t)b * C_ + c0) * S_ + s0;
  #pragma unroll
  for (int p = 0; p < 2; p++) {
    int c = cl + p * 32;
    int s = sq * 4;
    if (s0 + s < S_) {
      float4 v = *(const float4*)(sp + (size_t)c * S_ + s);
      tile[s + 0][c] = v.x; tile[s + 1][c] = v.y;
      tile[s + 2][c] = v.z; tile[s + 3][c] = v.w;
    }
  }
  __syncthreads();
  int sl = t >> 4, cq = t & 15;
  #pragma unroll
  for (int p = 0; p < 2; p++) {
    int s = sl + p * 16;
    if (s0 + s < S_) {
      us4 v;
      v.x = f2bf(tile[s][cq * 4 + 0]); v.y = f2bf(tile[s][cq * 4 + 1]);
      v.z = f2bf(tile[s][cq * 4 + 2]); v.w = f2bf(tile[s][cq * 4 + 3]);
      *(us4*)(dst + ((size_t)b * S_ + s0 + s) * C_ + c0 + cq * 4) = v;
    }
  }
}

// ---------------- u[b,h] = mean_t v_q[b,t,h] ----------------
__global__ void umean_k(const float* __restrict__ vq, float* __restrict__ u) {
  int b = blockIdx.y;
  int h = blockIdx.x * 256 + threadIdx.x;
  const float* p = vq + (size_t)b * T_ * HID_ + h;
  float s = 0.f;
  #pragma unroll
  for (int t = 0; t < T_; t++) s += p[t * HID_];
  u[(size_t)b * HID_ + h] = s * (1.f / T_);
}

// ---------------- vqt[b,k] = sum_h u[b,h]*w_u[k,h] + b_u[k] ----------------
__global__ void vqt_k(const float* __restrict__ u, const float* __restrict__ wu,
                      const float* __restrict__ bu, float* __restrict__ out) {
  __shared__ float us[32][64];
  __shared__ float ws[64][65];
  int k0 = blockIdx.x * 64, b0 = blockIdx.y * 32;
  int tid = threadIdx.x;
  int kl = tid & 63, bg = tid >> 6;
  float acc[8];
  #pragma unroll
  for (int j = 0; j < 8; j++) acc[j] = 0.f;
  for (int h0 = 0; h0 < HID_; h0 += 64) {
    __syncthreads();
    for (int idx = tid; idx < 32 * 16; idx += 256) {
      int bi = idx >> 4, jj = (idx & 15) * 4;
      *(float4*)&us[bi][jj] = *(const float4*)&u[(size_t)(b0 + bi) * HID_ + h0 + jj];
    }
    for (int idx = tid; idx < 64 * 16; idx += 256) {
      int ki = idx >> 4, jj = (idx & 15) * 4;
      float4 v = *(const float4*)&wu[(size_t)(k0 + ki) * HID_ + h0 + jj];
      ws[ki][jj] = v.x; ws[ki][jj + 1] = v.y; ws[ki][jj + 2] = v.z; ws[ki][jj + 3] = v.w;
    }
    __syncthreads();
    #pragma unroll 8
    for (int h = 0; h < 64; h++) {
      float wv = ws[kl][h];
      #pragma unroll
      for (int j = 0; j < 8; j++) acc[j] += wv * us[bg * 8 + j][h];
    }
  }
  #pragma unroll
  for (int j = 0; j < 8; j++)
    out[(size_t)(b0 + bg * 8 + j) * HID_ + k0 + kl] = acc[j] + bu[k0 + kl];
}

// ---------------- main GEMM: out[s,n] = sum_k A[b,s,k] * W[n,k] ----------------
// Block: 256 thr = 4 waves (2 mg x 2 ng), tile M=224 x N=128, BK=32, wave 112x64.
// SOFTWARE PIPELINE (this round's change): double-buffered LDS, ONE barrier/iter:
//   barrier -> prefetch tile k+1 into buf^1 (global_load_lds, no wait) -> compute
//   tile k from buf. The vmcnt(0) drain at the next barrier waits on loads that
//   had the whole compute phase (~1100 cyc) in flight -> L2 latency hidden,
//   vs r4's "stage; barrier; compute" which exposed it every iteration.
template<int KDIM, bool IS_HOP>
__global__ __launch_bounds__(256, 2)
void gemm_k(const __hip_bfloat16* __restrict__ Asrc,
            const __hip_bfloat16* __restrict__ Bw,
            const float* __restrict__ aux,      // l1: bias[1024]; hop: vqt[B][1024]
            __hip_bfloat16* __restrict__ vi_out,
            const __hip_bfloat16* __restrict__ vi_in,
            float* __restrict__ u) {
  constexpr int MSW = 7;
  constexpr int NIT = KDIM / 32;
  __shared__ short a_lds[2][896 * 8];           // 224 rows x 4 chunk-slots, dbuf
  __shared__ short b_lds[2][512 * 8];           // 128 rows x 4 chunk-slots, dbuf
  __shared__ float redb[2][128][2];             // hop cross-wave reduce

  const int id = blockIdx.x;
  const int b  = (id & 3) | ((id >> 5) << 2);
  const int n0 = ((id >> 2) & 7) * 128;
  const int tid  = threadIdx.x;
  const int wv   = tid >> 6;
  const int mg   = wv >> 1;
  const int ng   = wv & 1;
  const int lane = tid & 63;
  const int ln   = lane & 15;
  const int quad = lane >> 4;
  const int qsw  = quad ^ ((ln >> 1) & 3);

  const short* Ab = (const short*)(Asrc + (size_t)b * S_ * KDIM);
  const short* Bb = (const short*)Bw + (size_t)n0 * KDIM;

  // hoisted per-thread staging descriptors (k0 added in-loop)
  const short* aG[4];
  int aOff[4];
  #pragma unroll
  for (int p = 0; p < 4; p++) {
    int i = tid + p * 256;
    if (i < 896) {
      int m = i >> 2;
      int q = (i & 3) ^ ((i >> 3) & 3);
      int mc = (m < S_) ? m : (S_ - 1);
      aG[p]   = Ab + (size_t)mc * KDIM + q * 8;
      aOff[p] = i * 8;
    } else { aG[p] = nullptr; aOff[p] = 0; }
  }
  const short* bG[2];
  int bOff[2];
  #pragma unroll
  for (int p = 0; p < 2; p++) {
    int i = tid + p * 256;
    int n = i >> 2;
    int q = (i & 3) ^ ((i >> 3) & 3);
    bG[p]   = Bb + (size_t)n * KDIM + q * 8;
    bOff[p] = i * 8;
  }

  f32x4_t acc[MSW][4] = {};

  auto stage = [&](int k0, int buf) {
    #pragma unroll
    for (int p = 0; p < 4; p++)
      if (aG[p]) gl_lds16(aG[p] + k0, &a_lds[buf][aOff[p]]);
    #pragma unroll
    for (int p = 0; p < 2; p++)
      gl_lds16(bG[p] + k0, &b_lds[buf][bOff[p]]);
  };
  auto compute = [&](int buf) {
    s16x8 bf[4];
    #pragma unroll
    for (int j = 0; j < 4; j++)
      bf[j] = *(s16x8*)&b_lds[buf][((ng * 64 + j * 16 + ln) * 4 + qsw) * 8];
    #pragma unroll
    for (int ms = 0; ms < MSW; ms++) {
      s16x8 af = *(s16x8*)&a_lds[buf][((mg * 112 + ms * 16 + ln) * 4 + qsw) * 8];
      #pragma unroll
      for (int j = 0; j < 4; j++)
        acc[ms][j] = __builtin_amdgcn_mfma_f32_16x16x32_bf16(af, bf[j], acc[ms][j], 0, 0, 0);
    }
  };

  stage(0, 0);
  for (int it = 0; it < NIT; it += 2) {
    __syncthreads();                            // buf0 tile ready; buf1 reads done
    if (it + 1 < NIT) stage((it + 1) * 32, 1);  // prefetch next into buf1
    compute(0);
    __syncthreads();                            // buf1 tile ready; buf0 reads done
    if (it + 2 < NIT) stage((it + 2) * 32, 0);  // prefetch into buf0
    compute(1);
  }

  // C/D layout: col = lane&15, row = quad*4 + reg
  const int colb = ng * 64 + ln;
  if (!IS_HOP) {
    float bias[4];
    #pragma unroll
    for (int j = 0; j < 4; j++) bias[j] = aux[n0 + colb + j * 16];
    #pragma unroll
    for (int ms = 0; ms < MSW; ms++) {
      #pragma unroll
      for (int r = 0; r < 4; r++) {
        int row = mg * 112 + ms * 16 + quad * 4 + r;
        if (row < S_) {
          #pragma unroll
          for (int j = 0; j < 4; j++)
            vi_out[((size_t)b * S_ + row) * HID_ + n0 + colb + j * 16] =
                __float2bfloat16(fast_tanh(acc[ms][j][r] + bias[j]));
        }
      }
    }
  } else {
    float vq[4], mx[4];
    #pragma unroll
    for (int j = 0; j < 4; j++) {
      vq[j] = aux[(size_t)b * HID_ + n0 + colb + j * 16];
      mx[j] = -1e30f;
    }
    #pragma unroll
    for (int ms = 0; ms < MSW; ms++) {
      #pragma unroll
      for (int r = 0; r < 4; r++) {
        int row = mg * 112 + ms * 16 + quad * 4 + r;
        #pragma unroll
        for (int j = 0; j < 4; j++) {
          float v = (row < S_) ? fast_tanh(acc[ms][j][r] + vq[j]) : -1e30f;
          acc[ms][j][r] = v;
          mx[j] = fmaxf(mx[j], v);
        }
      }
    }
    #pragma unroll
    for (int j = 0; j < 4; j++) {
      mx[j] = fmaxf(mx[j], __shfl_xor(mx[j], 16));
      mx[j] = fmaxf(mx[j], __shfl_xor(mx[j], 32));
    }
    if (quad == 0) {
      #pragma unroll
      for (int j = 0; j < 4; j++) redb[mg][colb + j * 16][0] = mx[j];
    }
    __syncthreads();
    float gmx[4];
    #pragma unroll
    for (int j = 0; j < 4; j++)
      gmx[j] = fmaxf(mx[j], redb[1 - mg][colb + j * 16][0]);
    __syncthreads();
    float den[4] = {}, num[4] = {};
    const __hip_bfloat16* vb = vi_in + (size_t)b * S_ * HID_;
    #pragma unroll
    for (int ms = 0; ms < MSW; ms++) {
      #pragma unroll
      for (int r = 0; r < 4; r++) {
        int row = mg * 112 + ms * 16 + quad * 4 + r;
        if (row < S_) {
          #pragma unroll
          for (int j = 0; j < 4; j++) {
            float e = __expf(acc[ms][j][r] - gmx[j]);
            den[j] += e;
            num[j] += e * __bfloat162float(vb[(size_t)row * HID_ + n0 + colb + j * 16]);
          }
        }
      }
    }
    #pragma unroll
    for (int j = 0; j < 4; j++) {
      den[j] += __shfl_xor(den[j], 16); den[j] += __shfl_xor(den[j], 32);
      num[j] += __shfl_xor(num[j], 16); num[j] += __shfl_xor(num[j], 32);
    }
    if (quad == 0) {
      #pragma unroll
      for (int j = 0; j < 4; j++) {
        redb[mg][colb + j * 16][0] = den[j];
        redb[mg][colb + j * 16][1] = num[j];
      }
    }
    __syncthreads();
    if (mg == 0 && quad == 0) {
      #pragma unroll
      for (int j = 0; j < 4; j++) {
        int c = colb + j * 16;
        float d = redb[0][c][0] + redb[1][c][0];
        float n = redb[0][c][1] + redb[1][c][1];
        u[(size_t)b * HID_ + n0 + c] += n / d;
      }
    }
  }
}

extern "C" void kernel_launch(void* const* d_in, const int* in_sizes, int n_in,
                              void* d_out, int out_size, void* d_ws, size_t ws_size,
                              hipStream_t stream) {
  const float* v_i   = (const float*)d_in[0];
  const float* v_q   = (const float*)d_in[1];
  const float* l1_w  = (const float*)d_in[2];
  const float* l1_b  = (const float*)d_in[3];
  const float* w_vi0 = (const float*)d_in[4];
  const float* w_u0  = (const float*)d_in[5];
  const float* b_u0  = (const float*)d_in[6];
  const float* w_vi1 = (const float*)d_in[7];
  const float* w_u1  = (const float*)d_in[8];
  const float* b_u1  = (const float*)d_in[9];
  float* u = (float*)d_out;

  __hip_bfloat16* viT  = (__hip_bfloat16*)d_ws;                    // [B][S][C]
  __hip_bfloat16* vi   = viT + (size_t)B_ * S_ * C_;               // [B][S][HID]
  float*          vqt  = (float*)(vi + (size_t)B_ * S_ * HID_);    // [B][HID]
  __hip_bfloat16* l1wb = (__hip_bfloat16*)(vqt + (size_t)B_ * HID_);
  __hip_bfloat16* wv0b = l1wb + (size_t)HID_ * C_;
  __hip_bfloat16* wv1b = wv0b + (size_t)HID_ * HID_;

  // one launch converts all three weight matrices (dst contiguous)
  cvt3_k<<<dim3((HID_ * C_ + 2 * HID_ * HID_) / 1024), 256, 0, stream>>>(
      l1_w, w_vi0, w_vi1, l1wb);
  transpose_k<<<dim3(C_ / 64, 7, B_), 256, 0, stream>>>(v_i, viT);
  umean_k<<<dim3(HID_ / 256, B_), 256, 0, stream>>>(v_q, u);

  gemm_k<C_, false><<<dim3(1024), 256, 0, stream>>>(viT, l1wb, l1_b, vi, nullptr, nullptr);

  vqt_k<<<dim3(16, 4), 256, 0, stream>>>(u, w_u0, b_u0, vqt);
  gemm_k<HID_, true><<<dim3(1024), 256, 0, stream>>>(vi, wv0b, vqt, nullptr, vi, u);

  vqt_k<<<dim3(16, 4), 256, 0, stream>>>(u, w_u1, b_u1, vqt);
  gemm_k<HID_, true><<<dim3(1024), 256, 0, stream>>>(vi, wv1b, vqt, nullptr, vi, u);
}